// Round 8
// baseline (289.366 us; speedup 1.0000x reference)
//
#include <hip/hip_runtime.h>

typedef __attribute__((ext_vector_type(8))) short          bf16x8;
typedef __attribute__((ext_vector_type(8))) unsigned short u16x8;
typedef __attribute__((ext_vector_type(4))) unsigned short u16x4;
typedef __attribute__((ext_vector_type(4))) float          f32x4;
typedef __attribute__((ext_vector_type(4))) int            i32x4;
typedef __attribute__((ext_vector_type(4))) unsigned int   u32x4;

union U8 { u16x8 u; bf16x8 b; u32x4 w; };
union U4 { u16x4 u; unsigned w[2]; };

__device__ __forceinline__ unsigned short f2bf(float f){
  unsigned u = __float_as_uint(f);
  return (unsigned short)((u + 0x7fffu + ((u >> 16) & 1u)) >> 16);
}
// pack two floats to bf16x2 (round-half-up): lo->low16, hi->high16. exact 0 preserved.
__device__ __forceinline__ unsigned pack_bf16(float lo, float hi){
  unsigned a = __float_as_uint(hi) + 0x8000u;
  unsigned b = __float_as_uint(lo) + 0x8000u;
  return __builtin_amdgcn_perm(a, b, 0x07060302u);
}

#define NN  1024
#define FIN 256
#define NH  8
#define FO  64

// ---------------------------------------------------------------------------
// Stage 0: wfrag = w in MFMA-B-frag layout; Abits = bit-packed A;
//          out = bias*mz (pre-init for atomic merge).
// ---------------------------------------------------------------------------
__global__ __launch_bounds__(256) void stage0(
    const float* __restrict__ w, const int* __restrict__ A,
    const float* __restrict__ bias, const float* __restrict__ mz,
    unsigned short* __restrict__ wfrag, unsigned long long* __restrict__ Abits,
    float* __restrict__ out)
{
  const int tid = blockIdx.x * 256 + threadIdx.x;    // 262144 threads
  if (tid < 16384){
    const int lane = tid & 63, ss = (tid >> 6) & 3, kc = (tid >> 8) & 7, h = tid >> 11;
    const int o = 16 * ss + (lane & 15);
    const int f = kc * 32 + (lane >> 4) * 8;
    u16x8 r;
    #pragma unroll
    for (int j = 0; j < 8; j++) r[j] = f2bf(w[(h * FIN + f + j) * FO + o]);
    *(u16x8*)(wfrag + tid * 8) = r;
  }
  #pragma unroll
  for (int k = 0; k < 2; k++){                       // out = bias*mz
    const int i = tid + k * 262144;
    out[i] = bias[i & 63] * mz[i >> 6];
  }
  for (int i = tid; i < 8388608; i += 262144){       // adjacency bit-pack
    unsigned long long m = __ballot(A[i] > 0);
    if ((threadIdx.x & 63) == 0) Abits[i >> 6] = m;
  }
}

// ---------------------------------------------------------------------------
// Stage A: recx built in LDS per 16-row tile; h = recx @ w (MFMA);
// panel stores hT[b,h,mtile,o,32] + exp tables e^s, e^.2s, e^d, e^.2d.
// grid (64 tiles(16 rows), 8 b) = 512 blocks, block 512 (8 waves = 8 heads).
// ---------------------------------------------------------------------------
__global__ __launch_bounds__(512, 4) void stageA(
    const float* __restrict__ x, const float* __restrict__ e_at,
    const float* __restrict__ Np, const unsigned short* __restrict__ wfrag,
    const float* __restrict__ a_src, const float* __restrict__ a_dst,
    unsigned short* __restrict__ hT,
    float* __restrict__ exps, float* __restrict__ exps2,
    float* __restrict__ expd, float* __restrict__ expd2)
{
  __shared__ unsigned short rex[16 * 264];   // 16 rows x 256 f, pad 264
  const int t = threadIdx.x;
  const int n0 = blockIdx.x * 16, b = blockIdx.y;

  {                                          // cooperative recx tile build
    const int row = t >> 5, f0 = (t & 31) * 8;
    const int nrow = n0 + row;
    const float* ep = e_at + (b * NN + nrow) * FIN + f0;
    const float* qp = Np + nrow * FIN + f0;
    const float* xp = x + b * FIN + f0;
    f32x4 e0 = *(const f32x4*)ep, e1 = *(const f32x4*)(ep + 4);
    f32x4 q0 = *(const f32x4*)qp, q1 = *(const f32x4*)(qp + 4);
    f32x4 x0 = *(const f32x4*)xp, x1 = *(const f32x4*)(xp + 4);
    u16x8 r;
    #pragma unroll
    for (int j = 0; j < 4; j++){
      r[j]     = f2bf(e0[j] * q0[j] * x0[j]);
      r[j + 4] = f2bf(e1[j] * q1[j] * x1[j]);
    }
    *(u16x8*)(rex + row * 264 + f0) = r;
  }
  __syncthreads();

  const int h = t >> 6, lane = t & 63, quad = lane >> 4, l15 = lane & 15;
  const unsigned short* wf = wfrag + h * 16384 + lane * 8;

  f32x4 acc[4] = {};
  #pragma unroll
  for (int kc = 0; kc < 8; kc++){
    U8 a0, bf[4];
    a0.u = *(const u16x8*)(rex + l15 * 264 + kc * 32 + quad * 8);
    #pragma unroll
    for (int ss = 0; ss < 4; ss++) bf[ss].u = *(const u16x8*)(wf + (kc * 4 + ss) * 512);
    #pragma unroll
    for (int ss = 0; ss < 4; ss++)
      acc[ss] = __builtin_amdgcn_mfma_f32_16x16x32_bf16(a0.b, bf[ss].b, acc[ss], 0, 0, 0);
  }

  // panel store: [b,h,mtile,o(64),m(32)], C/D row(n)=quad*4+i, col(o)=16ss+l15
  {
    const int mtile = blockIdx.x >> 1, moff = (blockIdx.x & 1) * 16;
    unsigned short* pan = hT + (size_t)(((b * NH + h) * 32 + mtile) * 64) * 32;
    #pragma unroll
    for (int ss = 0; ss < 4; ss++){
      U4 v;
      v.w[0] = pack_bf16(acc[ss][0], acc[ss][1]);
      v.w[1] = pack_bf16(acc[ss][2], acc[ss][3]);
      *(u16x4*)(pan + (16 * ss + l15) * 32 + moff + quad * 4) = v.u;
    }
  }

  // s/d reductions -> exp tables
  float as4[4], ad4[4];
  #pragma unroll
  for (int ss = 0; ss < 4; ss++){
    as4[ss] = a_src[h * FO + 16 * ss + l15];
    ad4[ss] = a_dst[h * FO + 16 * ss + l15];
  }
  #pragma unroll
  for (int i = 0; i < 4; i++){
    float ps = 0.f, pd = 0.f;
    #pragma unroll
    for (int ss = 0; ss < 4; ss++){ ps += acc[ss][i] * as4[ss]; pd += acc[ss][i] * ad4[ss]; }
    #pragma unroll
    for (int off = 1; off < 16; off <<= 1){
      ps += __shfl_xor(ps, off);
      pd += __shfl_xor(pd, off);
    }
    if (l15 == 0){
      const int idx = (b * NH + h) * NN + n0 + quad * 4 + i;
      exps [idx] = __expf(ps);
      exps2[idx] = __expf(0.2f * ps);
      expd [idx] = __expf(pd);
      expd2[idx] = __expf(0.2f * pd);
    }
  }
}

// ---------------------------------------------------------------------------
// Phase L: l[b,h,n] = sum_m mask * max(Es*Ed, Es2*E2d); writes scaled
// esc[b,h,n] = (Es, Es2) * mz(n)/(8 l)  -> makes aggregation linear in (h,m).
// grid (16 row-blocks(64), 8 h, 8 b) = 1024 blocks, block 256.
// ---------------------------------------------------------------------------
__global__ __launch_bounds__(256, 4) void phaseL(
    const unsigned* __restrict__ Aw,
    const float* __restrict__ exps, const float* __restrict__ exps2,
    const float* __restrict__ expd, const float* __restrict__ expd2,
    const float* __restrict__ mz, float2* __restrict__ esc)
{
  __shared__ float ed[1024], e2[1024];
  const int t = threadIdx.x;
  const int h = blockIdx.y, b = blockIdx.z, bh = b * NH + h;
  *(f32x4*)(ed + t * 4) = *(const f32x4*)(expd  + bh * NN + t * 4);
  *(f32x4*)(e2 + t * 4) = *(const f32x4*)(expd2 + bh * NN + t * 4);
  __syncthreads();

  const int row = blockIdx.x * 64 + (t >> 2), q = t & 3;   // quarter-m per thread
  const float Es = exps[bh * NN + row], Es2 = exps2[bh * NN + row];
  const unsigned* mw = Aw + (b * NN + row) * 32 + q * 8;
  i32x4 w0 = *(const i32x4*)mw, w1 = *(const i32x4*)(mw + 4);

  float sum = 0.f;
  #pragma unroll
  for (int k = 0; k < 8; k++){
    const unsigned wd = (unsigned)((k < 4) ? w0[k] : w1[k - 4]);
    const int base = q * 256 + k * 32;
    #pragma unroll
    for (int g = 0; g < 8; g++){
      f32x4 dv = *(const f32x4*)(ed + base + g * 4);
      f32x4 gv = *(const f32x4*)(e2 + base + g * 4);
      #pragma unroll
      for (int j = 0; j < 4; j++){
        const float e = fmaxf(Es * dv[j], Es2 * gv[j]);
        sum += (wd & (1u << (g * 4 + j))) ? e : 0.f;
      }
    }
  }
  sum += __shfl_xor(sum, 1);
  sum += __shfl_xor(sum, 2);
  if (q == 0){
    const float s = 0.125f * mz[b * NN + row] / sum;
    float2 r; r.x = Es * s; r.y = Es2 * s;
    esc[bh * NN + row] = r;
  }
}

// ---------------------------------------------------------------------------
// Phase M: out += sum over this block's (h, m-octant) of P'' @ hT.
// grid (8 m-octants, 8 h, 8 b) = 512 blocks, block 512 (8 waves).
// hT slice (16 KB) + Ed slices LDS-resident (loaded once); inner loop is
// LDS + VALU + MFMA only; masks/esc prefetched depth-1 per n-tile.
// ---------------------------------------------------------------------------
__global__ __launch_bounds__(512, 4) void phaseM(
    const unsigned* __restrict__ Aw,
    const unsigned short* __restrict__ hT,
    const float* __restrict__ expd, const float* __restrict__ expd2,
    const float2* __restrict__ esc, float* __restrict__ out)
{
  __shared__ unsigned short pan[4 * 64 * 40];   // [c][o][m32] pad 40 -> 20 KB
  __shared__ float ed[128], e2[128];
  const int t = threadIdx.x;
  const int mo = blockIdx.x, h = blockIdx.y, b = blockIdx.z, bh = b * NH + h;

  {                                             // one-time pan slice load
    const unsigned short* src = hT + (size_t)(bh * 32 + mo * 4) * 2048 + t * 16;
    u16x8 v0 = *(const u16x8*)src;
    u16x8 v1 = *(const u16x8*)(src + 8);
    const int g = t * 16, c = g >> 11, rem = g & 2047, o = rem >> 5, m0 = rem & 31;
    unsigned short* dst = pan + (c * 64 + o) * 40 + m0;
    *(u16x8*)dst = v0;
    *(u16x8*)(dst + 8) = v1;
  }
  if (t < 32)      *(f32x4*)(ed + t * 4)        = *(const f32x4*)(expd  + bh * NN + mo * 128 + t * 4);
  else if (t < 64) *(f32x4*)(e2 + (t - 32) * 4) = *(const f32x4*)(expd2 + bh * NN + mo * 128 + (t - 32) * 4);
  __syncthreads();

  const int wv = t >> 6, lane = t & 63, quad = lane >> 4, l15 = lane & 15;
  const unsigned* Ab = Aw + (size_t)(b * NN) * 32 + mo * 4;
  const float2* ep = esc + bh * NN;

  i32x4 pm0 = *(const i32x4*)(Ab + (size_t)(wv * 32 + l15) * 32);
  i32x4 pm1 = *(const i32x4*)(Ab + (size_t)(wv * 32 + 16 + l15) * 32);
  float2 pe0 = ep[wv * 32 + l15];
  float2 pe1 = ep[wv * 32 + 16 + l15];

  for (int nt = wv; nt < 32; nt += 8){
    const i32x4 cm0 = pm0, cm1 = pm1;
    const float2 ce0 = pe0, ce1 = pe1;
    if (nt + 8 < 32){                            // depth-1 prefetch next n-tile
      pm0 = *(const i32x4*)(Ab + (size_t)((nt + 8) * 32 + l15) * 32);
      pm1 = *(const i32x4*)(Ab + (size_t)((nt + 8) * 32 + 16 + l15) * 32);
      pe0 = ep[(nt + 8) * 32 + l15];
      pe1 = ep[(nt + 8) * 32 + 16 + l15];
    }
    f32x4 acc[2][4] = {};
    #pragma unroll
    for (int c = 0; c < 4; c++){
      f32x4 dv0 = *(const f32x4*)(ed + c * 32 + quad * 8);
      f32x4 dv1 = *(const f32x4*)(ed + c * 32 + quad * 8 + 4);
      f32x4 gv0 = *(const f32x4*)(e2 + c * 32 + quad * 8);
      f32x4 gv1 = *(const f32x4*)(e2 + c * 32 + quad * 8 + 4);
      const unsigned a0 = ((unsigned)cm0[c]) >> (quad * 8);
      const unsigned a1 = ((unsigned)cm1[c]) >> (quad * 8);
      U8 p0, p1;
      #pragma unroll
      for (int r = 0; r < 4; r++){
        const int j0 = 2 * r, j1 = 2 * r + 1;
        const float d0 = (j0 < 4) ? dv0[j0] : dv1[j0 - 4];
        const float g0 = (j0 < 4) ? gv0[j0] : gv1[j0 - 4];
        const float d1 = (j1 < 4) ? dv0[j1] : dv1[j1 - 4];
        const float g1 = (j1 < 4) ? gv0[j1] : gv1[j1 - 4];
        float e00 = fmaxf(ce0.x * d0, ce0.y * g0);
        float e01 = fmaxf(ce0.x * d1, ce0.y * g1);
        float e10 = fmaxf(ce1.x * d0, ce1.y * g0);
        float e11 = fmaxf(ce1.x * d1, ce1.y * g1);
        e00 = (a0 & (1u << j0)) ? e00 : 0.f;
        e01 = (a0 & (1u << j1)) ? e01 : 0.f;
        e10 = (a1 & (1u << j0)) ? e10 : 0.f;
        e11 = (a1 & (1u << j1)) ? e11 : 0.f;
        p0.w[r] = pack_bf16(e00, e01);
        p1.w[r] = pack_bf16(e10, e11);
      }
      #pragma unroll
      for (int ss = 0; ss < 4; ss++){
        U8 pf;
        pf.u = *(const u16x8*)(pan + (c * 64 + 16 * ss + l15) * 40 + quad * 8);
        acc[0][ss] = __builtin_amdgcn_mfma_f32_16x16x32_bf16(p0.b, pf.b, acc[0][ss], 0, 0, 0);
        acc[1][ss] = __builtin_amdgcn_mfma_f32_16x16x32_bf16(p1.b, pf.b, acc[1][ss], 0, 0, 0);
      }
    }
    float* ob = out + (size_t)(b * NN + nt * 32) * FO;
    #pragma unroll
    for (int rg = 0; rg < 2; rg++)
      #pragma unroll
      for (int ss = 0; ss < 4; ss++)
        #pragma unroll
        for (int i = 0; i < 4; i++)
          atomicAdd(ob + (rg * 16 + quad * 4 + i) * FO + ss * 16 + l15, acc[rg][ss][i]);
  }
}

extern "C" void kernel_launch(void* const* d_in, const int* in_sizes, int n_in,
                              void* d_out, int out_size, void* d_ws, size_t ws_size,
                              hipStream_t stream)
{
  (void)in_sizes; (void)n_in; (void)out_size; (void)ws_size;
  const float* x    = (const float*)d_in[0];
  const int*   A    = (const int*)d_in[1];
  const float* mz   = (const float*)d_in[2];
  const float* e_at = (const float*)d_in[4];
  const float* Np   = (const float*)d_in[5];
  const float* w    = (const float*)d_in[6];
  const float* asrc = (const float*)d_in[7];
  const float* adst = (const float*)d_in[8];
  const float* bias = (const float*)d_in[9];
  float* out = (float*)d_out;

  char* ws = (char*)d_ws;
  unsigned short* wfrag = (unsigned short*)ws;                     // 256 KB
  unsigned short* hT    = (unsigned short*)(ws + 262144);          // 8 MB
  float* exps  = (float*)(ws + 8650752);                           // 256 KB
  float* exps2 = (float*)(ws + 8912896);                           // 256 KB
  float* expd  = (float*)(ws + 9175040);                           // 256 KB
  float* expd2 = (float*)(ws + 9437184);                           // 256 KB
  unsigned long long* Abits = (unsigned long long*)(ws + 9699328); // 1 MB
  float2* esc = (float2*)(ws + 10747904);                          // 512 KB

  stage0<<<dim3(1024), dim3(256), 0, stream>>>(w, A, bias, mz, wfrag, Abits, out);
  stageA<<<dim3(64, 8), dim3(512), 0, stream>>>(x, e_at, Np, wfrag, asrc, adst,
                                                hT, exps, exps2, expd, expd2);
  phaseL<<<dim3(16, 8, 8), dim3(256), 0, stream>>>((const unsigned*)Abits,
                                                   exps, exps2, expd, expd2, mz, esc);
  phaseM<<<dim3(8, 8, 8), dim3(512), 0, stream>>>((const unsigned*)Abits, hT,
                                                  expd, expd2, esc, out);
}